// Round 1
// baseline (558.026 us; speedup 1.0000x reference)
//
#include <hip/hip_runtime.h>

typedef unsigned short u16;
typedef unsigned int u32;
typedef __attribute__((ext_vector_type(8))) short bf16x8;
typedef __attribute__((ext_vector_type(4))) float f32x4;

// ---------- helpers ----------
__device__ __forceinline__ float bf2f(u16 u) {
    union { u32 i; float f; } x; x.i = ((u32)u) << 16; return x.f;
}
__device__ __forceinline__ u16 f2bf(float f) {
    union { float f; u32 i; } x; x.f = f;
    u32 u = x.i;
    u += 0x7FFFu + ((u >> 16) & 1u);   // RNE
    return (u16)(u >> 16);
}
__device__ __forceinline__ float wred(float v) {
    #pragma unroll
    for (int off = 32; off; off >>= 1) v += __shfl_down(v, off);
    return v;
}
__device__ __forceinline__ void gload_lds16(const void* g, void* l) {
    __builtin_amdgcn_global_load_lds(
        (const __attribute__((address_space(1))) u32*)g,
        (__attribute__((address_space(3))) u32*)l,
        16, 0, 0);
}

// ---------- conversion kernels ----------
__global__ __launch_bounds__(256)
void cvt_f32_bf16(const float* __restrict__ in, u16* __restrict__ out) {
    int i = (blockIdx.x * 256 + threadIdx.x) * 4;
    float4 v = *(const float4*)(in + i);
    ushort4 p;
    p.x = f2bf(v.x); p.y = f2bf(v.y); p.z = f2bf(v.z); p.w = f2bf(v.w);
    *(ushort4*)(out + i) = p;
}

// W [4096][4096] f32 -> Wt [4096][4096] bf16 with Wt[n][k] = W[k][n]
__global__ __launch_bounds__(256)
void transpose_cvt(const float* __restrict__ W, u16* __restrict__ Wt) {
    __shared__ float tile[32][33];
    int n0 = blockIdx.x * 32;
    int k0 = blockIdx.y * 32;
    int tx = threadIdx.x, ty = threadIdx.y;
    #pragma unroll
    for (int i = 0; i < 32; i += 8)
        tile[ty + i][tx] = W[(size_t)(k0 + ty + i) * 4096 + n0 + tx];
    __syncthreads();
    #pragma unroll
    for (int i = 0; i < 32; i += 8)
        Wt[(size_t)(n0 + ty + i) * 4096 + k0 + tx] = f2bf(tile[tx][ty + i]);
}

// W_wgen [4096][40] f32 -> WgT [40][4096] f32
__global__ __launch_bounds__(256)
void transpose_wgen(const float* __restrict__ W, float* __restrict__ Wt) {
    int idx = blockIdx.x * 256 + threadIdx.x;   // 163840 total
    int c = idx >> 12, e = idx & 4095;
    Wt[idx] = W[(size_t)e * 40 + c];
}

// ---------- GEMM: C[M][N] = A[M][K] @ Bt[N][K]^T (+bias, opt res+relu) ----------
// MODE 0: out = acc + bias[col]
// MODE 1: out = res + relu(acc + bias[col])
template <int MODE>
__global__ __launch_bounds__(256)
void gemm_bf16(const u16* __restrict__ A, const u16* __restrict__ Bt,
               const float* __restrict__ bias, const float* __restrict__ res,
               float* __restrict__ out) {
    const int K = 4096, N = 4096;
    __shared__ u16 Asm[128 * 32];   // 8 KB
    __shared__ u16 Bsm[128 * 32];   // 8 KB

    // XCD-aware swizzle (nwg = 1024, divisible by 8 -> bijective)
    int bid = blockIdx.x;
    int cpx = gridDim.x >> 3;
    int swz = (bid & 7) * cpx + (bid >> 3);
    int tm = swz >> 5;          // 32 N-tiles
    int tn = swz & 31;

    int tid = threadIdx.x;
    int lane = tid & 63;
    int wid = tid >> 6;
    int wr = wid >> 1, wc = wid & 1;   // 2x2 waves, 64x64 each

    const size_t rowA0 = (size_t)tm * 128;
    const size_t rowB0 = (size_t)tn * 128;

    f32x4 acc[4][4] = {};

    const int fr = lane & 15;
    const int fk = (lane >> 4) * 8;

    for (int k0 = 0; k0 < K; k0 += 32) {
        #pragma unroll
        for (int i = 0; i < 2; ++i) {
            int idx = i * 256 + tid;
            int r = idx >> 2;
            int kk = (idx & 3) * 8;
            gload_lds16(A  + (rowA0 + r) * K + k0 + kk, &Asm[idx * 8]);
            gload_lds16(Bt + (rowB0 + r) * K + k0 + kk, &Bsm[idx * 8]);
        }
        __syncthreads();
        bf16x8 af[4], bg[4];
        #pragma unroll
        for (int i = 0; i < 4; ++i)
            af[i] = *(const bf16x8*)&Asm[(wr * 64 + i * 16 + fr) * 32 + fk];
        #pragma unroll
        for (int j = 0; j < 4; ++j)
            bg[j] = *(const bf16x8*)&Bsm[(wc * 64 + j * 16 + fr) * 32 + fk];
        #pragma unroll
        for (int i = 0; i < 4; ++i)
            #pragma unroll
            for (int j = 0; j < 4; ++j)
                acc[i][j] = __builtin_amdgcn_mfma_f32_16x16x32_bf16(af[i], bg[j], acc[i][j], 0, 0, 0);
        __syncthreads();
    }

    const int cr = (lane >> 4) * 4;
    const int cc = lane & 15;
    #pragma unroll
    for (int i = 0; i < 4; ++i) {
        #pragma unroll
        for (int j = 0; j < 4; ++j) {
            size_t row = rowA0 + wr * 64 + i * 16 + cr;
            size_t col = rowB0 + wc * 64 + j * 16 + cc;
            float bv = bias[col];
            #pragma unroll
            for (int q = 0; q < 4; ++q) {
                size_t idx = (row + q) * N + col;
                float v = acc[i][j][q] + bv;
                if (MODE == 1) v = res[idx] + fmaxf(v, 0.0f);
                out[idx] = v;
            }
        }
    }
}

// ---------- LayerNorm + wgen + softmax (4 rows per block) ----------
__global__ __launch_bounds__(256)
void ln_wgen(const float* __restrict__ h, const float* __restrict__ g,
             const float* __restrict__ beta, const float* __restrict__ WgT,
             const float* __restrict__ bg, u16* __restrict__ y,
             float* __restrict__ w) {
    __shared__ u32 ylp[4][2048];   // 4 rows of bf16 pairs, 32 KB
    __shared__ float red[8];
    __shared__ float wraw[4][40];

    int tid = threadIdx.x, lane = tid & 63, wv = tid >> 6;
    size_t row0 = (size_t)blockIdx.x * 4;

    for (int r = 0; r < 4; ++r) {
        const float4* hr = (const float4*)(h + (row0 + r) * 4096);
        float4 v[4];
        float s = 0.f, ss = 0.f;
        #pragma unroll
        for (int i = 0; i < 4; ++i) {
            v[i] = hr[tid + i * 256];
            s  += v[i].x + v[i].y + v[i].z + v[i].w;
            ss += v[i].x * v[i].x + v[i].y * v[i].y + v[i].z * v[i].z + v[i].w * v[i].w;
        }
        s = wred(s); ss = wred(ss);
        if (lane == 0) { red[wv] = s; red[4 + wv] = ss; }
        __syncthreads();
        float S = red[0] + red[1] + red[2] + red[3];
        float SS = red[4] + red[5] + red[6] + red[7];
        float mu = S * (1.0f / 4096.0f);
        float var = SS * (1.0f / 4096.0f) - mu * mu;
        float inv = rsqrtf(var + 1e-5f);
        u16* yr = y + (row0 + r) * 4096;
        #pragma unroll
        for (int i = 0; i < 4; ++i) {
            int base = tid + i * 256;           // float4 index
            float4 gv = ((const float4*)g)[base];
            float4 bv = ((const float4*)beta)[base];
            float o0 = (v[i].x - mu) * inv * gv.x + bv.x;
            float o1 = (v[i].y - mu) * inv * gv.y + bv.y;
            float o2 = (v[i].z - mu) * inv * gv.z + bv.z;
            float o3 = (v[i].w - mu) * inv * gv.w + bv.w;
            u32 p01 = (u32)f2bf(o0) | ((u32)f2bf(o1) << 16);
            u32 p23 = (u32)f2bf(o2) | ((u32)f2bf(o3) << 16);
            ylp[r][base * 2]     = p01;
            ylp[r][base * 2 + 1] = p23;
            uint2 pk; pk.x = p01; pk.y = p23;
            *(uint2*)(yr + base * 4) = pk;
        }
        __syncthreads();   // protects red for next row, yl before wgen
    }

    // wgen: wave wv handles cols wv*10 .. wv*10+9
    #pragma unroll
    for (int c0 = 0; c0 < 10; ++c0) {
        int c = wv * 10 + c0;
        const float2* wc = (const float2*)(WgT + (size_t)c * 4096);
        float p0 = 0.f, p1 = 0.f, p2 = 0.f, p3 = 0.f;
        for (int eb = lane; eb < 2048; eb += 64) {
            float2 wg = wc[eb];
            u32 a0 = ylp[0][eb], a1 = ylp[1][eb], a2 = ylp[2][eb], a3 = ylp[3][eb];
            p0 += bf2f((u16)a0) * wg.x + bf2f((u16)(a0 >> 16)) * wg.y;
            p1 += bf2f((u16)a1) * wg.x + bf2f((u16)(a1 >> 16)) * wg.y;
            p2 += bf2f((u16)a2) * wg.x + bf2f((u16)(a2 >> 16)) * wg.y;
            p3 += bf2f((u16)a3) * wg.x + bf2f((u16)(a3 >> 16)) * wg.y;
        }
        p0 = wred(p0); p1 = wred(p1); p2 = wred(p2); p3 = wred(p3);
        if (lane == 0) {
            float bc = bg[c];
            wraw[0][c] = p0 + bc; wraw[1][c] = p1 + bc;
            wraw[2][c] = p2 + bc; wraw[3][c] = p3 + bc;
        }
    }
    __syncthreads();

    if (tid < 32) {
        int r = tid >> 3, hh = tid & 7;
        float e5[5];
        float mx = -1e30f;
        #pragma unroll
        for (int k = 0; k < 5; ++k) mx = fmaxf(mx, wraw[r][hh * 5 + k]);
        float sum = 0.f;
        #pragma unroll
        for (int k = 0; k < 5; ++k) { e5[k] = expf(wraw[r][hh * 5 + k] - mx); sum += e5[k]; }
        float isum = 1.0f / sum;
        float* wp = w + (row0 + r) * 40 + hh * 5;
        #pragma unroll
        for (int k = 0; k < 5; ++k) wp[k] = e5[k] * isum;
    }
}

// ---------- dynamic causal depthwise conv ----------
__global__ __launch_bounds__(256)
void dconv(const u16* __restrict__ y, const float* __restrict__ w,
           u16* __restrict__ conv) {
    int m = blockIdx.x;                       // 0..4095  (b*512 + t)
    int d0 = (blockIdx.y * 256 + threadIdx.x) * 8;
    int t = m & 511, b = m >> 9;
    int head = d0 >> 9;
    const float* wr = w + (size_t)m * 40 + head * 5;
    float acc[8] = {0.f,0.f,0.f,0.f,0.f,0.f,0.f,0.f};
    #pragma unroll
    for (int k = 0; k < 5; ++k) {
        int tt = t - 4 + k;
        if (tt < 0) continue;
        float wk = wr[k];
        uint4 v = *(const uint4*)(y + ((size_t)((b << 9) + tt) * 4096 + d0));
        const u16* us = (const u16*)&v;
        #pragma unroll
        for (int j = 0; j < 8; ++j) acc[j] += wk * bf2f(us[j]);
    }
    u16 o[8];
    #pragma unroll
    for (int j = 0; j < 8; ++j) o[j] = f2bf(acc[j]);
    *(uint4*)(conv + (size_t)m * 4096 + d0) = *(uint4*)o;
}

// ---------- launcher ----------
extern "C" void kernel_launch(void* const* d_in, const int* in_sizes, int n_in,
                              void* d_out, int out_size, void* d_ws, size_t ws_size,
                              hipStream_t stream) {
    const float* x      = (const float*)d_in[0];
    const float* W_proj = (const float*)d_in[1];
    const float* b_proj = (const float*)d_in[2];
    const float* ln_g   = (const float*)d_in[3];
    const float* ln_b   = (const float*)d_in[4];
    const float* W_wgen = (const float*)d_in[5];
    const float* b_wgen = (const float*)d_in[6];
    const float* W_ff   = (const float*)d_in[7];
    const float* b_ff   = (const float*)d_in[8];
    float* out = (float*)d_out;

    char* ws = (char*)d_ws;
    u16* xb   = (u16*)(ws);                          // 32 MB, later reused as conv
    u16* WpT  = (u16*)(ws + ((size_t)32 << 20));     // 32 MB, later reused as y
    u16* WfT  = (u16*)(ws + ((size_t)64 << 20));     // 32 MB
    float* wbuf = (float*)(ws + ((size_t)96 << 20)); // 640 KB
    float* WgT  = (float*)(ws + ((size_t)97 << 20)); // 640 KB
    u16* conv = xb;
    u16* ybuf = WpT;

    cvt_f32_bf16<<<16384, 256, 0, stream>>>(x, xb);
    dim3 tb(32, 8);
    transpose_cvt<<<dim3(128, 128), tb, 0, stream>>>(W_proj, WpT);
    transpose_cvt<<<dim3(128, 128), tb, 0, stream>>>(W_ff, WfT);
    transpose_wgen<<<640, 256, 0, stream>>>(W_wgen, WgT);

    gemm_bf16<0><<<1024, 256, 0, stream>>>(xb, WpT, b_proj, nullptr, out);
    ln_wgen<<<1024, 256, 0, stream>>>(out, ln_g, ln_b, WgT, b_wgen, ybuf, wbuf);
    dconv<<<dim3(4096, 2), 256, 0, stream>>>(ybuf, wbuf, conv);
    gemm_bf16<1><<<1024, 256, 0, stream>>>(conv, WfT, b_ff, out, out);
}

// Round 2
// 435.968 us; speedup vs baseline: 1.2800x; 1.2800x over previous
//
#include <hip/hip_runtime.h>

typedef unsigned short u16;
typedef unsigned int u32;
typedef __attribute__((ext_vector_type(8))) short bf16x8;
typedef __attribute__((ext_vector_type(4))) float f32x4;

// ---------- helpers ----------
__device__ __forceinline__ float bf2f(u16 u) {
    union { u32 i; float f; } x; x.i = ((u32)u) << 16; return x.f;
}
__device__ __forceinline__ u16 f2bf(float f) {
    union { float f; u32 i; } x; x.f = f;
    u32 u = x.i;
    u += 0x7FFFu + ((u >> 16) & 1u);   // RNE
    return (u16)(u >> 16);
}
__device__ __forceinline__ float wred(float v) {
    #pragma unroll
    for (int off = 32; off; off >>= 1) v += __shfl_down(v, off);
    return v;
}
__device__ __forceinline__ void gload_lds16(const void* g, void* l) {
    __builtin_amdgcn_global_load_lds(
        (const __attribute__((address_space(1))) u32*)g,
        (__attribute__((address_space(3))) u32*)l,
        16, 0, 0);
}

// ---------- conversion kernels ----------
__global__ __launch_bounds__(256)
void cvt_f32_bf16(const float* __restrict__ in, u16* __restrict__ out) {
    int i = (blockIdx.x * 256 + threadIdx.x) * 4;
    float4 v = *(const float4*)(in + i);
    ushort4 p;
    p.x = f2bf(v.x); p.y = f2bf(v.y); p.z = f2bf(v.z); p.w = f2bf(v.w);
    *(ushort4*)(out + i) = p;
}

// W [4096][4096] f32 -> Wt [4096][4096] bf16 with Wt[n][k] = W[k][n]
__global__ __launch_bounds__(256)
void transpose_cvt(const float* __restrict__ W, u16* __restrict__ Wt) {
    __shared__ float tile[32][33];
    int n0 = blockIdx.x * 32;
    int k0 = blockIdx.y * 32;
    int tx = threadIdx.x, ty = threadIdx.y;
    #pragma unroll
    for (int i = 0; i < 32; i += 8)
        tile[ty + i][tx] = W[(size_t)(k0 + ty + i) * 4096 + n0 + tx];
    __syncthreads();
    #pragma unroll
    for (int i = 0; i < 32; i += 8)
        Wt[(size_t)(n0 + ty + i) * 4096 + k0 + tx] = f2bf(tile[tx][ty + i]);
}

// W_wgen [4096][40] f32 -> WgT [40][4096] f32
__global__ __launch_bounds__(256)
void transpose_wgen(const float* __restrict__ W, float* __restrict__ Wt) {
    int idx = blockIdx.x * 256 + threadIdx.x;   // 163840 total
    int c = idx >> 12, e = idx & 4095;
    Wt[idx] = W[(size_t)e * 40 + c];
}

// ---------- 256x256 8-phase GEMM: C = A[M][K] @ Bt[N][K]^T (+bias, opt res+relu) ----
// MODE 0: out = acc + bias[col]
// MODE 1: out = res + relu(acc + bias[col])
template <int MODE>
__global__ __launch_bounds__(512, 2)
void gemm256(const u16* __restrict__ A, const u16* __restrict__ Bt,
             const float* __restrict__ bias, const float* __restrict__ res,
             float* __restrict__ out) {
    const int K = 4096, N = 4096;
    // [2 buffers][ A: 16384 u16 (256r x 64c) | B: 16384 u16 ] = 128 KB
    __shared__ u16 smem[65536];

    const int tid = threadIdx.x;
    const int lane = tid & 63;
    const int w = tid >> 6;            // 8 waves: 2 (M) x 4 (N)
    const int wr = w >> 2, wc = w & 3;
    const int fr = lane & 15;
    const int fk = (lane >> 4) * 8;
    const int cswz = (fr & 7) << 3;    // read-side XOR swizzle (elements)

    // XCD-aware bijective swizzle (256 blocks % 8 == 0)
    const int bid = blockIdx.x;
    const int swz = (bid & 7) * (gridDim.x >> 3) + (bid >> 3);
    const int tm = swz >> 4, tn = swz & 15;
    const size_t rowA0 = (size_t)tm * 256;
    const size_t rowB0 = (size_t)tn * 256;

    // staging: lane's linear LDS slot maps to inverse-swizzled global column
    const int srl = lane >> 3;                     // row within 8-row stripe
    const int scl = ((lane & 7) ^ srl) << 3;       // pre-swizzled col (elements)

    f32x4 acc[8][4] = {};
    bf16x8 af[8];   // current A quadrant: [m 0..3][k 0..1]
    bf16x8 bh[4];   // current B half:     [n 0..1][k 0..1]

    auto stA = [&](int b, int half, int kt) {
        #pragma unroll
        for (int i = 0; i < 2; ++i) {
            size_t grow = rowA0 + half * 128 + i * 64 + w * 8 + srl;
            gload_lds16(A + grow * K + kt * 64 + scl,
                        &smem[b * 32768 + half * 8192 + i * 4096 + w * 512 + lane * 8]);
        }
    };
    auto stB = [&](int b, int half, int kt) {
        #pragma unroll
        for (int i = 0; i < 2; ++i) {
            size_t grow = rowB0 + half * 128 + i * 64 + w * 8 + srl;
            gload_lds16(Bt + grow * K + kt * 64 + scl,
                        &smem[b * 32768 + 16384 + half * 8192 + i * 4096 + w * 512 + lane * 8]);
        }
    };
    auto ldA = [&](int b, int qm) {
        #pragma unroll
        for (int m = 0; m < 4; ++m) {
            int base = b * 32768 + (wr * 128 + (qm * 4 + m) * 16 + fr) * 64;
            af[m * 2 + 0] = *(const bf16x8*)&smem[base + (fk ^ cswz)];
            af[m * 2 + 1] = *(const bf16x8*)&smem[base + ((32 + fk) ^ cswz)];
        }
    };
    auto ldB = [&](int b, int qn) {
        #pragma unroll
        for (int n = 0; n < 2; ++n) {
            int base = b * 32768 + 16384 + (wc * 64 + (qn * 2 + n) * 16 + fr) * 64;
            bh[n * 2 + 0] = *(const bf16x8*)&smem[base + (fk ^ cswz)];
            bh[n * 2 + 1] = *(const bf16x8*)&smem[base + ((32 + fk) ^ cswz)];
        }
    };
    auto mma = [&](int qm, int qn) {
        __builtin_amdgcn_s_setprio(1);
        #pragma unroll
        for (int m = 0; m < 4; ++m)
            #pragma unroll
            for (int n = 0; n < 2; ++n) {
                acc[qm*4+m][qn*2+n] = __builtin_amdgcn_mfma_f32_16x16x32_bf16(
                    af[m*2+0], bh[n*2+0], acc[qm*4+m][qn*2+n], 0, 0, 0);
                acc[qm*4+m][qn*2+n] = __builtin_amdgcn_mfma_f32_16x16x32_bf16(
                    af[m*2+1], bh[n*2+1], acc[qm*4+m][qn*2+n], 0, 0, 0);
            }
        __builtin_amdgcn_s_setprio(0);
    };

    // prologue: tile0 fully + A halves of tile1  (12 loads in flight)
    stA(0, 0, 0); stA(0, 1, 0); stB(0, 0, 0); stB(0, 1, 0);
    stA(1, 0, 1); stA(1, 1, 1);
    asm volatile("s_waitcnt vmcnt(4)" ::: "memory");   // tile0 confirmed
    __builtin_amdgcn_s_barrier();

    // main loop: tiles 0..62 (tile 63 is the no-stage epilogue)
    for (int t = 0; t < 63; ++t) {
        const int b = t & 1, nb = b ^ 1;
        const int kt1 = t + 1;
        const int kt2 = (t + 2 < 64) ? t + 2 : 63;   // clamped garbage stage, never read
        // ph1: Q(0,0); stage B halves of t+1
        ldA(b, 0); ldB(b, 0);
        stB(nb, 0, kt1); stB(nb, 1, kt1);
        __builtin_amdgcn_s_barrier();
        mma(0, 0);
        __builtin_amdgcn_s_barrier();
        // ph2: Q(0,1)
        ldB(b, 1);
        __builtin_amdgcn_s_barrier();
        mma(0, 1);
        __builtin_amdgcn_s_barrier();
        // ph3: Q(1,1)
        ldA(b, 1);
        __builtin_amdgcn_s_barrier();
        mma(1, 1);
        __builtin_amdgcn_s_barrier();
        // ph4: Q(1,0); buf b A-region is free after ph3's barrier -> stage A of t+2
        ldB(b, 0);
        stA(b, 0, kt2); stA(b, 1, kt2);
        asm volatile("s_waitcnt vmcnt(4)" ::: "memory");  // confirms ALL of t+1, keeps 4 in flight
        __builtin_amdgcn_s_barrier();
        mma(1, 0);
        __builtin_amdgcn_s_barrier();
    }
    // epilogue tile 63 (buf 1) — data already confirmed
    {
        const int b = 1;
        ldA(b, 0); ldB(b, 0);
        __builtin_amdgcn_s_barrier();
        mma(0, 0);
        __builtin_amdgcn_s_barrier();
        ldB(b, 1);
        __builtin_amdgcn_s_barrier();
        mma(0, 1);
        __builtin_amdgcn_s_barrier();
        ldA(b, 1);
        __builtin_amdgcn_s_barrier();
        mma(1, 1);
        __builtin_amdgcn_s_barrier();
        ldB(b, 0);
        mma(1, 0);
    }

    // epilogue: C write (verified C/D layout: col=lane&15, row=(lane>>4)*4+q)
    const int cc = lane & 15;
    const int cr = (lane >> 4) * 4;
    #pragma unroll
    for (int m = 0; m < 8; ++m) {
        #pragma unroll
        for (int n = 0; n < 4; ++n) {
            size_t row = rowA0 + wr * 128 + m * 16 + cr;
            size_t col = rowB0 + wc * 64 + n * 16 + cc;
            float bv = bias[col];
            #pragma unroll
            for (int q = 0; q < 4; ++q) {
                size_t idx = (row + q) * (size_t)N + col;
                float v = acc[m][n][q] + bv;
                if (MODE == 1) v = res[idx] + fmaxf(v, 0.0f);
                out[idx] = v;
            }
        }
    }
}

// ---------- LayerNorm + wgen + softmax (4 rows per block) ----------
__global__ __launch_bounds__(256)
void ln_wgen(const float* __restrict__ h, const float* __restrict__ g,
             const float* __restrict__ beta, const float* __restrict__ WgT,
             const float* __restrict__ bg, u16* __restrict__ y,
             float* __restrict__ w) {
    __shared__ u32 ylp[4][2048];   // 4 rows of bf16 pairs, 32 KB
    __shared__ float red[8];
    __shared__ float wraw[4][40];

    int tid = threadIdx.x, lane = tid & 63, wv = tid >> 6;
    size_t row0 = (size_t)blockIdx.x * 4;

    for (int r = 0; r < 4; ++r) {
        const float4* hr = (const float4*)(h + (row0 + r) * 4096);
        float4 v[4];
        float s = 0.f, ss = 0.f;
        #pragma unroll
        for (int i = 0; i < 4; ++i) {
            v[i] = hr[tid + i * 256];
            s  += v[i].x + v[i].y + v[i].z + v[i].w;
            ss += v[i].x * v[i].x + v[i].y * v[i].y + v[i].z * v[i].z + v[i].w * v[i].w;
        }
        s = wred(s); ss = wred(ss);
        if (lane == 0) { red[wv] = s; red[4 + wv] = ss; }
        __syncthreads();
        float S = red[0] + red[1] + red[2] + red[3];
        float SS = red[4] + red[5] + red[6] + red[7];
        float mu = S * (1.0f / 4096.0f);
        float var = SS * (1.0f / 4096.0f) - mu * mu;
        float inv = rsqrtf(var + 1e-5f);
        u16* yr = y + (row0 + r) * 4096;
        #pragma unroll
        for (int i = 0; i < 4; ++i) {
            int base = tid + i * 256;           // float4 index
            float4 gv = ((const float4*)g)[base];
            float4 bv = ((const float4*)beta)[base];
            float o0 = (v[i].x - mu) * inv * gv.x + bv.x;
            float o1 = (v[i].y - mu) * inv * gv.y + bv.y;
            float o2 = (v[i].z - mu) * inv * gv.z + bv.z;
            float o3 = (v[i].w - mu) * inv * gv.w + bv.w;
            u32 p01 = (u32)f2bf(o0) | ((u32)f2bf(o1) << 16);
            u32 p23 = (u32)f2bf(o2) | ((u32)f2bf(o3) << 16);
            ylp[r][base * 2]     = p01;
            ylp[r][base * 2 + 1] = p23;
            uint2 pk; pk.x = p01; pk.y = p23;
            *(uint2*)(yr + base * 4) = pk;
        }
        __syncthreads();   // protects red for next row, yl before wgen
    }

    // wgen: wave wv handles cols wv*10 .. wv*10+9
    #pragma unroll
    for (int c0 = 0; c0 < 10; ++c0) {
        int c = wv * 10 + c0;
        const float2* wc = (const float2*)(WgT + (size_t)c * 4096);
        float p0 = 0.f, p1 = 0.f, p2 = 0.f, p3 = 0.f;
        for (int eb = lane; eb < 2048; eb += 64) {
            float2 wg = wc[eb];
            u32 a0 = ylp[0][eb], a1 = ylp[1][eb], a2 = ylp[2][eb], a3 = ylp[3][eb];
            p0 += bf2f((u16)a0) * wg.x + bf2f((u16)(a0 >> 16)) * wg.y;
            p1 += bf2f((u16)a1) * wg.x + bf2f((u16)(a1 >> 16)) * wg.y;
            p2 += bf2f((u16)a2) * wg.x + bf2f((u16)(a2 >> 16)) * wg.y;
            p3 += bf2f((u16)a3) * wg.x + bf2f((u16)(a3 >> 16)) * wg.y;
        }
        p0 = wred(p0); p1 = wred(p1); p2 = wred(p2); p3 = wred(p3);
        if (lane == 0) {
            float bc = bg[c];
            wraw[0][c] = p0 + bc; wraw[1][c] = p1 + bc;
            wraw[2][c] = p2 + bc; wraw[3][c] = p3 + bc;
        }
    }
    __syncthreads();

    if (tid < 32) {
        int r = tid >> 3, hh = tid & 7;
        float e5[5];
        float mx = -1e30f;
        #pragma unroll
        for (int k = 0; k < 5; ++k) mx = fmaxf(mx, wraw[r][hh * 5 + k]);
        float sum = 0.f;
        #pragma unroll
        for (int k = 0; k < 5; ++k) { e5[k] = expf(wraw[r][hh * 5 + k] - mx); sum += e5[k]; }
        float isum = 1.0f / sum;
        float* wp = w + (row0 + r) * 40 + hh * 5;
        #pragma unroll
        for (int k = 0; k < 5; ++k) wp[k] = e5[k] * isum;
    }
}

// ---------- dynamic causal depthwise conv ----------
__global__ __launch_bounds__(256)
void dconv(const u16* __restrict__ y, const float* __restrict__ w,
           u16* __restrict__ conv) {
    int m = blockIdx.x;                       // 0..4095  (b*512 + t)
    int d0 = (blockIdx.y * 256 + threadIdx.x) * 8;
    int t = m & 511, b = m >> 9;
    int head = d0 >> 9;
    const float* wr = w + (size_t)m * 40 + head * 5;
    float acc[8] = {0.f,0.f,0.f,0.f,0.f,0.f,0.f,0.f};
    #pragma unroll
    for (int k = 0; k < 5; ++k) {
        int tt = t - 4 + k;
        if (tt < 0) continue;
        float wk = wr[k];
        uint4 v = *(const uint4*)(y + ((size_t)((b << 9) + tt) * 4096 + d0));
        const u16* us = (const u16*)&v;
        #pragma unroll
        for (int j = 0; j < 8; ++j) acc[j] += wk * bf2f(us[j]);
    }
    u16 o[8];
    #pragma unroll
    for (int j = 0; j < 8; ++j) o[j] = f2bf(acc[j]);
    *(uint4*)(conv + (size_t)m * 4096 + d0) = *(uint4*)o;
}

// ---------- launcher ----------
extern "C" void kernel_launch(void* const* d_in, const int* in_sizes, int n_in,
                              void* d_out, int out_size, void* d_ws, size_t ws_size,
                              hipStream_t stream) {
    const float* x      = (const float*)d_in[0];
    const float* W_proj = (const float*)d_in[1];
    const float* b_proj = (const float*)d_in[2];
    const float* ln_g   = (const float*)d_in[3];
    const float* ln_b   = (const float*)d_in[4];
    const float* W_wgen = (const float*)d_in[5];
    const float* b_wgen = (const float*)d_in[6];
    const float* W_ff   = (const float*)d_in[7];
    const float* b_ff   = (const float*)d_in[8];
    float* out = (float*)d_out;

    char* ws = (char*)d_ws;
    u16* xb   = (u16*)(ws);                          // 32 MB, later reused as conv
    u16* WpT  = (u16*)(ws + ((size_t)32 << 20));     // 32 MB, later reused as y
    u16* WfT  = (u16*)(ws + ((size_t)64 << 20));     // 32 MB
    float* wbuf = (float*)(ws + ((size_t)96 << 20)); // 640 KB
    float* WgT  = (float*)(ws + ((size_t)97 << 20)); // 640 KB
    u16* conv = xb;
    u16* ybuf = WpT;

    cvt_f32_bf16<<<16384, 256, 0, stream>>>(x, xb);
    dim3 tb(32, 8);
    transpose_cvt<<<dim3(128, 128), tb, 0, stream>>>(W_proj, WpT);
    transpose_cvt<<<dim3(128, 128), tb, 0, stream>>>(W_ff, WfT);
    transpose_wgen<<<640, 256, 0, stream>>>(W_wgen, WgT);

    gemm256<0><<<256, 512, 0, stream>>>(xb, WpT, b_proj, nullptr, out);
    ln_wgen<<<1024, 256, 0, stream>>>(out, ln_g, ln_b, WgT, b_wgen, ybuf, wbuf);
    dconv<<<dim3(4096, 2), 256, 0, stream>>>(ybuf, wbuf, conv);
    gemm256<1><<<256, 512, 0, stream>>>(conv, WfT, b_ff, out, out);
}

// Round 3
// 424.272 us; speedup vs baseline: 1.3153x; 1.0276x over previous
//
#include <hip/hip_runtime.h>

typedef unsigned short u16;
typedef unsigned int u32;
typedef __attribute__((ext_vector_type(8))) short bf16x8;
typedef __attribute__((ext_vector_type(4))) float f32x4;

// ---------- helpers ----------
__device__ __forceinline__ float bf2f(u16 u) {
    union { u32 i; float f; } x; x.i = ((u32)u) << 16; return x.f;
}
__device__ __forceinline__ u16 f2bf(float f) {
    union { float f; u32 i; } x; x.f = f;
    u32 u = x.i;
    u += 0x7FFFu + ((u >> 16) & 1u);   // RNE
    return (u16)(u >> 16);
}
__device__ __forceinline__ float wred(float v) {
    #pragma unroll
    for (int off = 32; off; off >>= 1) v += __shfl_down(v, off);
    return v;
}
__device__ __forceinline__ void gload_lds16(const void* g, void* l) {
    __builtin_amdgcn_global_load_lds(
        (const __attribute__((address_space(1))) u32*)g,
        (__attribute__((address_space(3))) u32*)l,
        16, 0, 0);
}

// ---------- conversion kernels ----------
__global__ __launch_bounds__(256)
void cvt_f32_bf16(const float* __restrict__ in, u16* __restrict__ out) {
    int i = (blockIdx.x * 256 + threadIdx.x) * 4;
    float4 v = *(const float4*)(in + i);
    ushort4 p;
    p.x = f2bf(v.x); p.y = f2bf(v.y); p.z = f2bf(v.z); p.w = f2bf(v.w);
    *(ushort4*)(out + i) = p;
}

// W [4096][4096] f32 -> Wt [4096][4096] bf16 with Wt[n][k] = W[k][n]
__global__ __launch_bounds__(256)
void transpose_cvt(const float* __restrict__ W, u16* __restrict__ Wt) {
    __shared__ float tile[32][33];
    int n0 = blockIdx.x * 32;
    int k0 = blockIdx.y * 32;
    int tx = threadIdx.x, ty = threadIdx.y;
    #pragma unroll
    for (int i = 0; i < 32; i += 8)
        tile[ty + i][tx] = W[(size_t)(k0 + ty + i) * 4096 + n0 + tx];
    __syncthreads();
    #pragma unroll
    for (int i = 0; i < 32; i += 8)
        Wt[(size_t)(n0 + ty + i) * 4096 + k0 + tx] = f2bf(tile[tx][ty + i]);
}

// W_wgen [4096][40] f32 -> WgT [40][4096] f32
__global__ __launch_bounds__(256)
void transpose_wgen(const float* __restrict__ W, float* __restrict__ Wt) {
    int idx = blockIdx.x * 256 + threadIdx.x;   // 163840 total
    int c = idx >> 12, e = idx & 4095;
    Wt[idx] = W[(size_t)e * 40 + c];
}

// ---------- 256x256 8-phase GEMM: C = A[M][K] @ Bt[N][K]^T (+bias, opt res+relu) ----
// Template schedule: 2 K-tiles per iteration, 1 half-tile staged per phase,
// counted vmcnt(4) at phases 4 and 8 only (never drained to 0 in the loop).
// MODE 0: out = acc + bias[col]
// MODE 1: out = res + relu(acc + bias[col])
template <int MODE>
__global__ __launch_bounds__(512, 2)
void gemm256(const u16* __restrict__ A, const u16* __restrict__ Bt,
             const float* __restrict__ bias, const float* __restrict__ res,
             float* __restrict__ out) {
    const int K = 4096, N = 4096;
    // [2 buffers][ A: 16384 u16 (256r x 64c) | B: 16384 u16 ] = 128 KB
    __shared__ u16 smem[65536];

    const int tid = threadIdx.x;
    const int lane = tid & 63;
    const int w = tid >> 6;            // 8 waves: 2 (M) x 4 (N)
    const int wr = w >> 2, wc = w & 3;
    const int fr = lane & 15;
    const int fk = (lane >> 4) * 8;
    const int cswz = (fr & 7) << 3;    // read-side XOR swizzle (elements)

    // XCD-aware bijective swizzle (256 blocks % 8 == 0)
    const int bid = blockIdx.x;
    const int swz = (bid & 7) * (gridDim.x >> 3) + (bid >> 3);
    const int tm = swz >> 4, tn = swz & 15;
    const size_t rowA0 = (size_t)tm * 256;
    const size_t rowB0 = (size_t)tn * 256;

    // staging: lane's linear LDS slot maps to inverse-swizzled global column
    const int srl = lane >> 3;                     // row within 8-row stripe
    const int scl = ((lane & 7) ^ srl) << 3;       // pre-swizzled col (elements)

    f32x4 acc[8][4] = {};
    bf16x8 af[8];    // current A quadrant: [m 0..3][k 0..1]
    bf16x8 bh0[4];   // B cols wc*64 + 0..31   [n 0..1][k 0..1]
    bf16x8 bh1[4];   // B cols wc*64 + 32..63

    auto stA = [&](int b, int half, int kt) {
        #pragma unroll
        for (int i = 0; i < 2; ++i) {
            size_t grow = rowA0 + half * 128 + i * 64 + w * 8 + srl;
            gload_lds16(A + grow * K + kt * 64 + scl,
                        &smem[b * 32768 + half * 8192 + i * 4096 + w * 512 + lane * 8]);
        }
    };
    auto stB = [&](int b, int half, int kt) {
        #pragma unroll
        for (int i = 0; i < 2; ++i) {
            size_t grow = rowB0 + half * 128 + i * 64 + w * 8 + srl;
            gload_lds16(Bt + grow * K + kt * 64 + scl,
                        &smem[b * 32768 + 16384 + half * 8192 + i * 4096 + w * 512 + lane * 8]);
        }
    };
    auto ldA = [&](int b, int qm) {
        #pragma unroll
        for (int m = 0; m < 4; ++m) {
            int base = b * 32768 + (wr * 128 + (qm * 4 + m) * 16 + fr) * 64;
            af[m * 2 + 0] = *(const bf16x8*)&smem[base + (fk ^ cswz)];
            af[m * 2 + 1] = *(const bf16x8*)&smem[base + ((32 + fk) ^ cswz)];
        }
    };
    auto ldB = [&](int b, int qn, bf16x8 (&bh)[4]) {
        #pragma unroll
        for (int n = 0; n < 2; ++n) {
            int base = b * 32768 + 16384 + (wc * 64 + qn * 32 + n * 16 + fr) * 64;
            bh[n * 2 + 0] = *(const bf16x8*)&smem[base + (fk ^ cswz)];
            bh[n * 2 + 1] = *(const bf16x8*)&smem[base + ((32 + fk) ^ cswz)];
        }
    };
    auto mma = [&](int qm, int qn, bf16x8 (&bh)[4]) {
        __builtin_amdgcn_s_setprio(1);
        #pragma unroll
        for (int m = 0; m < 4; ++m)
            #pragma unroll
            for (int n = 0; n < 2; ++n) {
                acc[qm*4+m][qn*2+n] = __builtin_amdgcn_mfma_f32_16x16x32_bf16(
                    af[m*2+0], bh[n*2+0], acc[qm*4+m][qn*2+n], 0, 0, 0);
                acc[qm*4+m][qn*2+n] = __builtin_amdgcn_mfma_f32_16x16x32_bf16(
                    af[m*2+1], bh[n*2+1], acc[qm*4+m][qn*2+n], 0, 0, 0);
            }
        __builtin_amdgcn_s_setprio(0);
    };
    #define BAR() __builtin_amdgcn_s_barrier()
    #define VM4() asm volatile("s_waitcnt vmcnt(4)" ::: "memory")

    // prologue: tile0 fully + B halves of tile1 (12 loads); confirm tile0
    stB(0, 0, 0); stB(0, 1, 0); stA(0, 0, 0); stA(0, 1, 0);
    stB(1, 0, 1); stB(1, 1, 1);
    VM4();
    BAR();

    // 32 uniform iterations, tiles (2i, 2i+1) in (buf0, buf1)
    for (int i = 0; i < 32; ++i) {
        const int t = 2 * i;
        const int kt2 = (t + 2 < 64) ? t + 2 : 63;   // clamped: rewrites dead region
        const int kt3 = (t + 3 < 64) ? t + 3 : 63;
        // p1: tile t, Q(0,0)
        ldA(0, 0); ldB(0, 0, bh0);
        stA(1, 0, t + 1);
        BAR(); mma(0, 0, bh0); BAR();
        // p2: Q(0,1)
        ldB(0, 1, bh1);
        stA(1, 1, t + 1);
        BAR(); mma(0, 1, bh1); BAR();
        // p3: Q(1,1)
        ldA(0, 1);
        stB(0, 0, kt2);
        BAR(); mma(1, 1, bh1); BAR();
        // p4: Q(1,0) — bh0 held in regs; confirm tile t+1 (keep 2 halves in flight)
        stB(0, 1, kt2);
        VM4();
        BAR(); mma(1, 0, bh0); BAR();
        // p5: tile t+1, Q(0,0)
        ldA(1, 0); ldB(1, 0, bh0);
        stA(0, 0, kt2);
        BAR(); mma(0, 0, bh0); BAR();
        // p6: Q(0,1)
        ldB(1, 1, bh1);
        stA(0, 1, kt2);
        BAR(); mma(0, 1, bh1); BAR();
        // p7: Q(1,1)
        ldA(1, 1);
        stB(1, 0, kt3);
        BAR(); mma(1, 1, bh1); BAR();
        // p8: Q(1,0) — confirm tile t+2
        stB(1, 1, kt3);
        VM4();
        BAR(); mma(1, 0, bh0); BAR();
    }
    #undef BAR
    #undef VM4

    // epilogue: C write (verified C/D layout: col=lane&15, row=(lane>>4)*4+q)
    const int cc = lane & 15;
    const int cr = (lane >> 4) * 4;
    #pragma unroll
    for (int m = 0; m < 8; ++m) {
        #pragma unroll
        for (int n = 0; n < 4; ++n) {
            size_t row = rowA0 + wr * 128 + m * 16 + cr;
            size_t col = rowB0 + wc * 64 + n * 16 + cc;
            float bv = bias[col];
            #pragma unroll
            for (int q = 0; q < 4; ++q) {
                size_t idx = (row + q) * (size_t)N + col;
                float v = acc[m][n][q] + bv;
                if (MODE == 1) v = res[idx] + fmaxf(v, 0.0f);
                out[idx] = v;
            }
        }
    }
}

// ---------- LayerNorm + wgen + softmax (4 rows per block) ----------
__global__ __launch_bounds__(256)
void ln_wgen(const float* __restrict__ h, const float* __restrict__ g,
             const float* __restrict__ beta, const float* __restrict__ WgT,
             const float* __restrict__ bg, u16* __restrict__ y,
             float* __restrict__ w) {
    __shared__ u32 ylp[4][2048];   // 4 rows of bf16 pairs, 32 KB
    __shared__ float red[8];
    __shared__ float wraw[4][40];

    int tid = threadIdx.x, lane = tid & 63, wv = tid >> 6;
    size_t row0 = (size_t)blockIdx.x * 4;

    for (int r = 0; r < 4; ++r) {
        const float4* hr = (const float4*)(h + (row0 + r) * 4096);
        float4 v[4];
        float s = 0.f, ss = 0.f;
        #pragma unroll
        for (int i = 0; i < 4; ++i) {
            v[i] = hr[tid + i * 256];
            s  += v[i].x + v[i].y + v[i].z + v[i].w;
            ss += v[i].x * v[i].x + v[i].y * v[i].y + v[i].z * v[i].z + v[i].w * v[i].w;
        }
        s = wred(s); ss = wred(ss);
        if (lane == 0) { red[wv] = s; red[4 + wv] = ss; }
        __syncthreads();
        float S = red[0] + red[1] + red[2] + red[3];
        float SS = red[4] + red[5] + red[6] + red[7];
        float mu = S * (1.0f / 4096.0f);
        float var = SS * (1.0f / 4096.0f) - mu * mu;
        float inv = rsqrtf(var + 1e-5f);
        u16* yr = y + (row0 + r) * 4096;
        #pragma unroll
        for (int i = 0; i < 4; ++i) {
            int base = tid + i * 256;           // float4 index
            float4 gv = ((const float4*)g)[base];
            float4 bv = ((const float4*)beta)[base];
            float o0 = (v[i].x - mu) * inv * gv.x + bv.x;
            float o1 = (v[i].y - mu) * inv * gv.y + bv.y;
            float o2 = (v[i].z - mu) * inv * gv.z + bv.z;
            float o3 = (v[i].w - mu) * inv * gv.w + bv.w;
            u32 p01 = (u32)f2bf(o0) | ((u32)f2bf(o1) << 16);
            u32 p23 = (u32)f2bf(o2) | ((u32)f2bf(o3) << 16);
            ylp[r][base * 2]     = p01;
            ylp[r][base * 2 + 1] = p23;
            uint2 pk; pk.x = p01; pk.y = p23;
            *(uint2*)(yr + base * 4) = pk;
        }
        __syncthreads();   // protects red for next row, yl before wgen
    }

    // wgen: wave wv handles cols wv*10 .. wv*10+9
    #pragma unroll
    for (int c0 = 0; c0 < 10; ++c0) {
        int c = wv * 10 + c0;
        const float2* wc = (const float2*)(WgT + (size_t)c * 4096);
        float p0 = 0.f, p1 = 0.f, p2 = 0.f, p3 = 0.f;
        for (int eb = lane; eb < 2048; eb += 64) {
            float2 wg = wc[eb];
            u32 a0 = ylp[0][eb], a1 = ylp[1][eb], a2 = ylp[2][eb], a3 = ylp[3][eb];
            p0 += bf2f((u16)a0) * wg.x + bf2f((u16)(a0 >> 16)) * wg.y;
            p1 += bf2f((u16)a1) * wg.x + bf2f((u16)(a1 >> 16)) * wg.y;
            p2 += bf2f((u16)a2) * wg.x + bf2f((u16)(a2 >> 16)) * wg.y;
            p3 += bf2f((u16)a3) * wg.x + bf2f((u16)(a3 >> 16)) * wg.y;
        }
        p0 = wred(p0); p1 = wred(p1); p2 = wred(p2); p3 = wred(p3);
        if (lane == 0) {
            float bc = bg[c];
            wraw[0][c] = p0 + bc; wraw[1][c] = p1 + bc;
            wraw[2][c] = p2 + bc; wraw[3][c] = p3 + bc;
        }
    }
    __syncthreads();

    if (tid < 32) {
        int r = tid >> 3, hh = tid & 7;
        float e5[5];
        float mx = -1e30f;
        #pragma unroll
        for (int k = 0; k < 5; ++k) mx = fmaxf(mx, wraw[r][hh * 5 + k]);
        float sum = 0.f;
        #pragma unroll
        for (int k = 0; k < 5; ++k) { e5[k] = expf(wraw[r][hh * 5 + k] - mx); sum += e5[k]; }
        float isum = 1.0f / sum;
        float* wp = w + (row0 + r) * 40 + hh * 5;
        #pragma unroll
        for (int k = 0; k < 5; ++k) wp[k] = e5[k] * isum;
    }
}

// ---------- dynamic causal depthwise conv ----------
__global__ __launch_bounds__(256)
void dconv(const u16* __restrict__ y, const float* __restrict__ w,
           u16* __restrict__ conv) {
    int m = blockIdx.x;                       // 0..4095  (b*512 + t)
    int d0 = (blockIdx.y * 256 + threadIdx.x) * 8;
    int t = m & 511, b = m >> 9;
    int head = d0 >> 9;
    const float* wr = w + (size_t)m * 40 + head * 5;
    float acc[8] = {0.f,0.f,0.f,0.f,0.f,0.f,0.f,0.f};
    #pragma unroll
    for (int k = 0; k < 5; ++k) {
        int tt = t - 4 + k;
        if (tt < 0) continue;
        float wk = wr[k];
        uint4 v = *(const uint4*)(y + ((size_t)((b << 9) + tt) * 4096 + d0));
        const u16* us = (const u16*)&v;
        #pragma unroll
        for (int j = 0; j < 8; ++j) acc[j] += wk * bf2f(us[j]);
    }
    u16 o[8];
    #pragma unroll
    for (int j = 0; j < 8; ++j) o[j] = f2bf(acc[j]);
    *(uint4*)(conv + (size_t)m * 4096 + d0) = *(uint4*)o;
}

// ---------- launcher ----------
extern "C" void kernel_launch(void* const* d_in, const int* in_sizes, int n_in,
                              void* d_out, int out_size, void* d_ws, size_t ws_size,
                              hipStream_t stream) {
    const float* x      = (const float*)d_in[0];
    const float* W_proj = (const float*)d_in[1];
    const float* b_proj = (const float*)d_in[2];
    const float* ln_g   = (const float*)d_in[3];
    const float* ln_b   = (const float*)d_in[4];
    const float* W_wgen = (const float*)d_in[5];
    const float* b_wgen = (const float*)d_in[6];
    const float* W_ff   = (const float*)d_in[7];
    const float* b_ff   = (const float*)d_in[8];
    float* out = (float*)d_out;

    char* ws = (char*)d_ws;
    u16* xb   = (u16*)(ws);                          // 32 MB, later reused as conv
    u16* WpT  = (u16*)(ws + ((size_t)32 << 20));     // 32 MB, later reused as y
    u16* WfT  = (u16*)(ws + ((size_t)64 << 20));     // 32 MB
    float* wbuf = (float*)(ws + ((size_t)96 << 20)); // 640 KB
    float* WgT  = (float*)(ws + ((size_t)97 << 20)); // 640 KB
    u16* conv = xb;
    u16* ybuf = WpT;

    cvt_f32_bf16<<<16384, 256, 0, stream>>>(x, xb);
    dim3 tb(32, 8);
    transpose_cvt<<<dim3(128, 128), tb, 0, stream>>>(W_proj, WpT);
    transpose_cvt<<<dim3(128, 128), tb, 0, stream>>>(W_ff, WfT);
    transpose_wgen<<<640, 256, 0, stream>>>(W_wgen, WgT);

    gemm256<0><<<256, 512, 0, stream>>>(xb, WpT, b_proj, nullptr, out);
    ln_wgen<<<1024, 256, 0, stream>>>(out, ln_g, ln_b, WgT, b_wgen, ybuf, wbuf);
    dconv<<<dim3(4096, 2), 256, 0, stream>>>(ybuf, wbuf, conv);
    gemm256<1><<<256, 512, 0, stream>>>(conv, WfT, b_ff, out, out);
}

// Round 4
// 413.722 us; speedup vs baseline: 1.3488x; 1.0255x over previous
//
#include <hip/hip_runtime.h>

typedef unsigned short u16;
typedef unsigned int u32;
typedef __attribute__((ext_vector_type(8))) short bf16x8;
typedef __attribute__((ext_vector_type(4))) float f32x4;

// ---------- helpers ----------
__device__ __forceinline__ float bf2f(u16 u) {
    union { u32 i; float f; } x; x.i = ((u32)u) << 16; return x.f;
}
__device__ __forceinline__ u16 f2bf(float f) {
    union { float f; u32 i; } x; x.f = f;
    u32 u = x.i;
    u += 0x7FFFu + ((u >> 16) & 1u);   // RNE
    return (u16)(u >> 16);
}
__device__ __forceinline__ float wred(float v) {
    #pragma unroll
    for (int off = 32; off; off >>= 1) v += __shfl_down(v, off);
    return v;
}
__device__ __forceinline__ void gload_lds16(const void* g, void* l) {
    __builtin_amdgcn_global_load_lds(
        (const __attribute__((address_space(1))) u32*)g,
        (__attribute__((address_space(3))) u32*)l,
        16, 0, 0);
}

// ---------- conversion kernels ----------
__global__ __launch_bounds__(256)
void cvt_f32_bf16(const float* __restrict__ in, u16* __restrict__ out) {
    int i = (blockIdx.x * 256 + threadIdx.x) * 4;
    float4 v = *(const float4*)(in + i);
    ushort4 p;
    p.x = f2bf(v.x); p.y = f2bf(v.y); p.z = f2bf(v.z); p.w = f2bf(v.w);
    *(ushort4*)(out + i) = p;
}

// W [4096][4096] f32 -> Wt [4096][4096] bf16 with Wt[n][k] = W[k][n]
__global__ __launch_bounds__(256)
void transpose_cvt(const float* __restrict__ W, u16* __restrict__ Wt) {
    __shared__ float tile[32][33];
    int n0 = blockIdx.x * 32;
    int k0 = blockIdx.y * 32;
    int tx = threadIdx.x, ty = threadIdx.y;
    #pragma unroll
    for (int i = 0; i < 32; i += 8)
        tile[ty + i][tx] = W[(size_t)(k0 + ty + i) * 4096 + n0 + tx];
    __syncthreads();
    #pragma unroll
    for (int i = 0; i < 32; i += 8)
        Wt[(size_t)(n0 + ty + i) * 4096 + k0 + tx] = f2bf(tile[tx][ty + i]);
}

// W_wgen [4096][40] f32 -> WgT [40][4096] f32
__global__ __launch_bounds__(256)
void transpose_wgen(const float* __restrict__ W, float* __restrict__ Wt) {
    int idx = blockIdx.x * 256 + threadIdx.x;   // 163840 total
    int c = idx >> 12, e = idx & 4095;
    Wt[idx] = W[(size_t)e * 40 + c];
}

// ---------- 256x256 8-phase GEMM: C = A[M][K] @ Bt[N][K]^T (+bias, opt res+relu) ----
// ONE barrier per phase. Stage-at-p requires target's last reader at phase <= p-2
// (reader drains via lgkmcnt before MFMA, which precedes its arrival at B(p-1)).
// vmcnt(4) at phases 4 and 8 only; in-flight peaks at 12, never drained to 0.
// MODE 0: out = acc + bias[col]
// MODE 1: out = res + relu(acc + bias[col])
template <int MODE>
__global__ __launch_bounds__(512, 2)
void gemm256(const u16* __restrict__ A, const u16* __restrict__ Bt,
             const float* __restrict__ bias, const float* __restrict__ res,
             float* __restrict__ out) {
    const int K = 4096, N = 4096;
    // [2 buffers][ A: 16384 u16 (256r x 64c) | B: 16384 u16 ] = 128 KB
    __shared__ u16 smem[65536];

    const int tid = threadIdx.x;
    const int lane = tid & 63;
    const int w = tid >> 6;            // 8 waves: 2 (M) x 4 (N)
    const int wr = w >> 2, wc = w & 3;
    const int fr = lane & 15;
    const int fk = (lane >> 4) * 8;
    const int cswz = (fr & 7) << 3;    // read-side XOR swizzle (elements)

    // XCD-aware bijective swizzle (256 blocks % 8 == 0)
    const int bid = blockIdx.x;
    const int swz = (bid & 7) * (gridDim.x >> 3) + (bid >> 3);
    const int tm = swz >> 4, tn = swz & 15;
    const size_t rowA0 = (size_t)tm * 256;
    const size_t rowB0 = (size_t)tn * 256;

    // staging: lane's linear LDS slot maps to inverse-swizzled global column
    const int srl = lane >> 3;                     // row within 8-row stripe
    const int scl = ((lane & 7) ^ srl) << 3;       // pre-swizzled col (elements)

    f32x4 acc[8][4] = {};
    bf16x8 af[8];    // current A quadrant: [m 0..3][k 0..1]
    bf16x8 bh0[4];   // B cols wc*64 + 0..31   [n 0..1][k 0..1]
    bf16x8 bh1[4];   // B cols wc*64 + 32..63

    auto stA = [&](int b, int half, int kt) {
        #pragma unroll
        for (int i = 0; i < 2; ++i) {
            size_t grow = rowA0 + half * 128 + i * 64 + w * 8 + srl;
            gload_lds16(A + grow * K + kt * 64 + scl,
                        &smem[b * 32768 + half * 8192 + i * 4096 + w * 512 + lane * 8]);
        }
    };
    auto stB = [&](int b, int half, int kt) {
        #pragma unroll
        for (int i = 0; i < 2; ++i) {
            size_t grow = rowB0 + half * 128 + i * 64 + w * 8 + srl;
            gload_lds16(Bt + grow * K + kt * 64 + scl,
                        &smem[b * 32768 + 16384 + half * 8192 + i * 4096 + w * 512 + lane * 8]);
        }
    };
    auto ldA = [&](int b, int qm) {
        #pragma unroll
        for (int m = 0; m < 4; ++m) {
            int base = b * 32768 + (wr * 128 + (qm * 4 + m) * 16 + fr) * 64;
            af[m * 2 + 0] = *(const bf16x8*)&smem[base + (fk ^ cswz)];
            af[m * 2 + 1] = *(const bf16x8*)&smem[base + ((32 + fk) ^ cswz)];
        }
    };
    auto ldB = [&](int b, int qn, bf16x8 (&bh)[4]) {
        #pragma unroll
        for (int n = 0; n < 2; ++n) {
            int base = b * 32768 + 16384 + (wc * 64 + qn * 32 + n * 16 + fr) * 64;
            bh[n * 2 + 0] = *(const bf16x8*)&smem[base + (fk ^ cswz)];
            bh[n * 2 + 1] = *(const bf16x8*)&smem[base + ((32 + fk) ^ cswz)];
        }
    };
    auto mma = [&](int qm, int qn, bf16x8 (&bh)[4]) {
        __builtin_amdgcn_s_setprio(1);
        #pragma unroll
        for (int m = 0; m < 4; ++m)
            #pragma unroll
            for (int n = 0; n < 2; ++n) {
                acc[qm*4+m][qn*2+n] = __builtin_amdgcn_mfma_f32_16x16x32_bf16(
                    af[m*2+0], bh[n*2+0], acc[qm*4+m][qn*2+n], 0, 0, 0);
                acc[qm*4+m][qn*2+n] = __builtin_amdgcn_mfma_f32_16x16x32_bf16(
                    af[m*2+1], bh[n*2+1], acc[qm*4+m][qn*2+n], 0, 0, 0);
            }
        __builtin_amdgcn_s_setprio(0);
    };
    #define BAR() __builtin_amdgcn_s_barrier()
    #define VM4() asm volatile("s_waitcnt vmcnt(4)" ::: "memory")

    // prologue: tile0 fully + B halves of tile1 (12 loads); confirm tile0
    stB(0, 0, 0); stB(0, 1, 0); stA(0, 0, 0); stA(0, 1, 0);
    stB(1, 0, 1); stB(1, 1, 1);
    VM4();
    BAR();

    // 32 uniform iterations, tiles (2i, 2i+1) in (buf0, buf1)
    for (int i = 0; i < 32; ++i) {
        const int t = 2 * i;
        const int kt2 = (t + 2 < 64) ? t + 2 : 63;   // clamped: rewrites identical data
        const int kt3 = (t + 3 < 64) ? t + 3 : 63;
        // p1: tile t, Q(0,0); stage A(t+1) half0 (old last read prev-p7)
        ldA(0, 0); ldB(0, 0, bh0);
        stA(1, 0, t + 1);
        BAR(); mma(0, 0, bh0);
        // p2: Q(0,1); stage A(t+1) half1
        ldB(0, 1, bh1);
        stA(1, 1, t + 1);
        BAR(); mma(0, 1, bh1);
        // p3: Q(1,1); no stage (buf0.B last read at p2 -> too close)
        ldA(0, 1);
        BAR(); mma(1, 1, bh1);
        // p4: Q(1,0); stage B(t+2) (last read p2, distance 2 OK); confirm tile t+1
        stB(0, 0, kt2); stB(0, 1, kt2);
        VM4();
        BAR(); mma(1, 0, bh0);
        // p5: tile t+1, Q(0,0); stage A(t+2) half0 (buf0.A last read p3)
        ldA(1, 0); ldB(1, 0, bh0);
        stA(0, 0, kt2);
        BAR(); mma(0, 0, bh0);
        // p6: Q(0,1); stage A(t+2) half1
        ldB(1, 1, bh1);
        stA(0, 1, kt2);
        BAR(); mma(0, 1, bh1);
        // p7: Q(1,1); no stage
        ldA(1, 1);
        BAR(); mma(1, 1, bh1);
        // p8: Q(1,0); stage B(t+3) (buf1.B last read p6, distance 2); confirm t+2
        stB(1, 0, kt3); stB(1, 1, kt3);
        VM4();
        BAR(); mma(1, 0, bh0);
    }
    #undef BAR
    #undef VM4

    // epilogue: C write (verified C/D layout: col=lane&15, row=(lane>>4)*4+q)
    const int cc = lane & 15;
    const int cr = (lane >> 4) * 4;
    #pragma unroll
    for (int m = 0; m < 8; ++m) {
        #pragma unroll
        for (int n = 0; n < 4; ++n) {
            size_t row = rowA0 + wr * 128 + m * 16 + cr;
            size_t col = rowB0 + wc * 64 + n * 16 + cc;
            float bv = bias[col];
            #pragma unroll
            for (int q = 0; q < 4; ++q) {
                size_t idx = (row + q) * (size_t)N + col;
                float v = acc[m][n][q] + bv;
                if (MODE == 1) v = res[idx] + fmaxf(v, 0.0f);
                out[idx] = v;
            }
        }
    }
}

// ---------- LayerNorm + wgen + softmax (4 rows per block) ----------
__global__ __launch_bounds__(256)
void ln_wgen(const float* __restrict__ h, const float* __restrict__ g,
             const float* __restrict__ beta, const float* __restrict__ WgT,
             const float* __restrict__ bg, u16* __restrict__ y,
             float* __restrict__ w) {
    __shared__ u32 ylp[4][2048];   // 4 rows of bf16 pairs, 32 KB
    __shared__ float red[8];
    __shared__ float wraw[4][40];

    int tid = threadIdx.x, lane = tid & 63, wv = tid >> 6;
    size_t row0 = (size_t)blockIdx.x * 4;

    for (int r = 0; r < 4; ++r) {
        const float4* hr = (const float4*)(h + (row0 + r) * 4096);
        float4 v[4];
        float s = 0.f, ss = 0.f;
        #pragma unroll
        for (int i = 0; i < 4; ++i) {
            v[i] = hr[tid + i * 256];
            s  += v[i].x + v[i].y + v[i].z + v[i].w;
            ss += v[i].x * v[i].x + v[i].y * v[i].y + v[i].z * v[i].z + v[i].w * v[i].w;
        }
        s = wred(s); ss = wred(ss);
        if (lane == 0) { red[wv] = s; red[4 + wv] = ss; }
        __syncthreads();
        float S = red[0] + red[1] + red[2] + red[3];
        float SS = red[4] + red[5] + red[6] + red[7];
        float mu = S * (1.0f / 4096.0f);
        float var = SS * (1.0f / 4096.0f) - mu * mu;
        float inv = rsqrtf(var + 1e-5f);
        u16* yr = y + (row0 + r) * 4096;
        #pragma unroll
        for (int i = 0; i < 4; ++i) {
            int base = tid + i * 256;           // float4 index
            float4 gv = ((const float4*)g)[base];
            float4 bv = ((const float4*)beta)[base];
            float o0 = (v[i].x - mu) * inv * gv.x + bv.x;
            float o1 = (v[i].y - mu) * inv * gv.y + bv.y;
            float o2 = (v[i].z - mu) * inv * gv.z + bv.z;
            float o3 = (v[i].w - mu) * inv * gv.w + bv.w;
            u32 p01 = (u32)f2bf(o0) | ((u32)f2bf(o1) << 16);
            u32 p23 = (u32)f2bf(o2) | ((u32)f2bf(o3) << 16);
            ylp[r][base * 2]     = p01;
            ylp[r][base * 2 + 1] = p23;
            uint2 pk; pk.x = p01; pk.y = p23;
            *(uint2*)(yr + base * 4) = pk;
        }
        __syncthreads();   // protects red for next row, yl before wgen
    }

    // wgen: wave wv handles cols wv*10 .. wv*10+9
    #pragma unroll
    for (int c0 = 0; c0 < 10; ++c0) {
        int c = wv * 10 + c0;
        const float2* wc = (const float2*)(WgT + (size_t)c * 4096);
        float p0 = 0.f, p1 = 0.f, p2 = 0.f, p3 = 0.f;
        for (int eb = lane; eb < 2048; eb += 64) {
            float2 wg = wc[eb];
            u32 a0 = ylp[0][eb], a1 = ylp[1][eb], a2 = ylp[2][eb], a3 = ylp[3][eb];
            p0 += bf2f((u16)a0) * wg.x + bf2f((u16)(a0 >> 16)) * wg.y;
            p1 += bf2f((u16)a1) * wg.x + bf2f((u16)(a1 >> 16)) * wg.y;
            p2 += bf2f((u16)a2) * wg.x + bf2f((u16)(a2 >> 16)) * wg.y;
            p3 += bf2f((u16)a3) * wg.x + bf2f((u16)(a3 >> 16)) * wg.y;
        }
        p0 = wred(p0); p1 = wred(p1); p2 = wred(p2); p3 = wred(p3);
        if (lane == 0) {
            float bc = bg[c];
            wraw[0][c] = p0 + bc; wraw[1][c] = p1 + bc;
            wraw[2][c] = p2 + bc; wraw[3][c] = p3 + bc;
        }
    }
    __syncthreads();

    if (tid < 32) {
        int r = tid >> 3, hh = tid & 7;
        float e5[5];
        float mx = -1e30f;
        #pragma unroll
        for (int k = 0; k < 5; ++k) mx = fmaxf(mx, wraw[r][hh * 5 + k]);
        float sum = 0.f;
        #pragma unroll
        for (int k = 0; k < 5; ++k) { e5[k] = expf(wraw[r][hh * 5 + k] - mx); sum += e5[k]; }
        float isum = 1.0f / sum;
        float* wp = w + (row0 + r) * 40 + hh * 5;
        #pragma unroll
        for (int k = 0; k < 5; ++k) wp[k] = e5[k] * isum;
    }
}

// ---------- dynamic causal depthwise conv ----------
__global__ __launch_bounds__(256)
void dconv(const u16* __restrict__ y, const float* __restrict__ w,
           u16* __restrict__ conv) {
    int m = blockIdx.x;                       // 0..4095  (b*512 + t)
    int d0 = (blockIdx.y * 256 + threadIdx.x) * 8;
    int t = m & 511, b = m >> 9;
    int head = d0 >> 9;
    const float* wr = w + (size_t)m * 40 + head * 5;
    float acc[8] = {0.f,0.f,0.f,0.f,0.f,0.f,0.f,0.f};
    #pragma unroll
    for (int k = 0; k < 5; ++k) {
        int tt = t - 4 + k;
        if (tt < 0) continue;
        float wk = wr[k];
        uint4 v = *(const uint4*)(y + ((size_t)((b << 9) + tt) * 4096 + d0));
        const u16* us = (const u16*)&v;
        #pragma unroll
        for (int j = 0; j < 8; ++j) acc[j] += wk * bf2f(us[j]);
    }
    u16 o[8];
    #pragma unroll
    for (int j = 0; j < 8; ++j) o[j] = f2bf(acc[j]);
    *(uint4*)(conv + (size_t)m * 4096 + d0) = *(uint4*)o;
}

// ---------- launcher ----------
extern "C" void kernel_launch(void* const* d_in, const int* in_sizes, int n_in,
                              void* d_out, int out_size, void* d_ws, size_t ws_size,
                              hipStream_t stream) {
    const float* x      = (const float*)d_in[0];
    const float* W_proj = (const float*)d_in[1];
    const float* b_proj = (const float*)d_in[2];
    const float* ln_g   = (const float*)d_in[3];
    const float* ln_b   = (const float*)d_in[4];
    const float* W_wgen = (const float*)d_in[5];
    const float* b_wgen = (const float*)d_in[6];
    const float* W_ff   = (const float*)d_in[7];
    const float* b_ff   = (const float*)d_in[8];
    float* out = (float*)d_out;

    char* ws = (char*)d_ws;
    u16* xb   = (u16*)(ws);                          // 32 MB, later reused as conv
    u16* WpT  = (u16*)(ws + ((size_t)32 << 20));     // 32 MB, later reused as y
    u16* WfT  = (u16*)(ws + ((size_t)64 << 20));     // 32 MB
    float* wbuf = (float*)(ws + ((size_t)96 << 20)); // 640 KB
    float* WgT  = (float*)(ws + ((size_t)97 << 20)); // 640 KB
    u16* conv = xb;
    u16* ybuf = WpT;

    cvt_f32_bf16<<<16384, 256, 0, stream>>>(x, xb);
    dim3 tb(32, 8);
    transpose_cvt<<<dim3(128, 128), tb, 0, stream>>>(W_proj, WpT);
    transpose_cvt<<<dim3(128, 128), tb, 0, stream>>>(W_ff, WfT);
    transpose_wgen<<<640, 256, 0, stream>>>(W_wgen, WgT);

    gemm256<0><<<256, 512, 0, stream>>>(xb, WpT, b_proj, nullptr, out);
    ln_wgen<<<1024, 256, 0, stream>>>(out, ln_g, ln_b, WgT, b_wgen, ybuf, wbuf);
    dconv<<<dim3(4096, 2), 256, 0, stream>>>(ybuf, wbuf, conv);
    gemm256<1><<<256, 512, 0, stream>>>(conv, WfT, b_ff, out, out);
}

// Round 5
// 359.209 us; speedup vs baseline: 1.5535x; 1.1518x over previous
//
#include <hip/hip_runtime.h>

typedef unsigned short u16;
typedef unsigned int u32;
typedef __attribute__((ext_vector_type(8))) short bf16x8;
typedef __attribute__((ext_vector_type(4))) float f32x4;

// ---------- helpers ----------
__device__ __forceinline__ float bf2f(u16 u) {
    union { u32 i; float f; } x; x.i = ((u32)u) << 16; return x.f;
}
__device__ __forceinline__ u16 f2bf(float f) {
    union { float f; u32 i; } x; x.f = f;
    u32 u = x.i;
    u += 0x7FFFu + ((u >> 16) & 1u);   // RNE
    return (u16)(u >> 16);
}
__device__ __forceinline__ float wred(float v) {
    #pragma unroll
    for (int off = 32; off; off >>= 1) v += __shfl_down(v, off);
    return v;
}
__device__ __forceinline__ void gload_lds16(const void* g, void* l) {
    __builtin_amdgcn_global_load_lds(
        (const __attribute__((address_space(1))) u32*)g,
        (__attribute__((address_space(3))) u32*)l,
        16, 0, 0);
}

// ---------- conversion kernels ----------
__global__ __launch_bounds__(256)
void cvt_f32_bf16(const float* __restrict__ in, u16* __restrict__ out) {
    int i = (blockIdx.x * 256 + threadIdx.x) * 4;
    float4 v = *(const float4*)(in + i);
    ushort4 p;
    p.x = f2bf(v.x); p.y = f2bf(v.y); p.z = f2bf(v.z); p.w = f2bf(v.w);
    *(ushort4*)(out + i) = p;
}

// W [4096][4096] f32 -> Wt [4096][4096] bf16 with Wt[n][k] = W[k][n]
// 64x64 tile; loads 128B/wave-row, stores ushort2 (128B/wave-row)
__global__ __launch_bounds__(256)
void transpose_cvt(const float* __restrict__ W, u16* __restrict__ Wt) {
    __shared__ float tile[64][65];
    int n0 = blockIdx.x * 64;
    int k0 = blockIdx.y * 64;
    int tx = threadIdx.x, ty = threadIdx.y;   // (32, 8)
    #pragma unroll
    for (int i = 0; i < 8; ++i) {
        int kk = ty + i * 8;
        const float* src = W + (size_t)(k0 + kk) * 4096 + n0;
        tile[kk][tx]      = src[tx];
        tile[kk][tx + 32] = src[tx + 32];
    }
    __syncthreads();
    #pragma unroll
    for (int i = 0; i < 8; ++i) {
        int nn = ty + i * 8;
        ushort2 p;
        p.x = f2bf(tile[tx * 2][nn]);
        p.y = f2bf(tile[tx * 2 + 1][nn]);
        *(ushort2*)(Wt + (size_t)(n0 + nn) * 4096 + k0 + tx * 2) = p;
    }
}

// W_wgen [4096][40] f32 -> WgT [40][4096] f32
__global__ __launch_bounds__(256)
void transpose_wgen(const float* __restrict__ W, float* __restrict__ Wt) {
    int idx = blockIdx.x * 256 + threadIdx.x;   // 163840 total
    int c = idx >> 12, e = idx & 4095;
    Wt[idx] = W[(size_t)e * 40 + c];
}

// ---------- 256x256 8-phase GEMM: C = A[M][K] @ Bt[N][K]^T (+bias, opt res+relu) ----
// ONE barrier per phase. Stage-at-p requires target's last reader at phase <= p-2.
// vmcnt(4) at phases 4 and 8 only; in-flight peaks at 12, never drained to 0.
template <int MODE>
__global__ __launch_bounds__(512, 2)
void gemm256(const u16* __restrict__ A, const u16* __restrict__ Bt,
             const float* __restrict__ bias, const float* __restrict__ res,
             float* __restrict__ out) {
    const int K = 4096, N = 4096;
    __shared__ u16 smem[65536];   // 128 KB: [2 buf][A 16384 | B 16384]

    const int tid = threadIdx.x;
    const int lane = tid & 63;
    const int w = tid >> 6;            // 8 waves: 2 (M) x 4 (N)
    const int wr = w >> 2, wc = w & 3;
    const int fr = lane & 15;
    const int fk = (lane >> 4) * 8;
    const int cswz = (fr & 7) << 3;    // read-side XOR swizzle (elements)

    const int bid = blockIdx.x;
    const int swz = (bid & 7) * (gridDim.x >> 3) + (bid >> 3);
    const int tm = swz >> 4, tn = swz & 15;
    const size_t rowA0 = (size_t)tm * 256;
    const size_t rowB0 = (size_t)tn * 256;

    const int srl = lane >> 3;                     // row within 8-row stripe
    const int scl = ((lane & 7) ^ srl) << 3;       // pre-swizzled col (elements)

    f32x4 acc[8][4] = {};
    bf16x8 af[8];    // current A quadrant
    bf16x8 bh0[4];   // B cols wc*64 + 0..31
    bf16x8 bh1[4];   // B cols wc*64 + 32..63

    auto stA = [&](int b, int half, int kt) {
        #pragma unroll
        for (int i = 0; i < 2; ++i) {
            size_t grow = rowA0 + half * 128 + i * 64 + w * 8 + srl;
            gload_lds16(A + grow * K + kt * 64 + scl,
                        &smem[b * 32768 + half * 8192 + i * 4096 + w * 512 + lane * 8]);
        }
    };
    auto stB = [&](int b, int half, int kt) {
        #pragma unroll
        for (int i = 0; i < 2; ++i) {
            size_t grow = rowB0 + half * 128 + i * 64 + w * 8 + srl;
            gload_lds16(Bt + grow * K + kt * 64 + scl,
                        &smem[b * 32768 + 16384 + half * 8192 + i * 4096 + w * 512 + lane * 8]);
        }
    };
    auto ldA = [&](int b, int qm) {
        #pragma unroll
        for (int m = 0; m < 4; ++m) {
            int base = b * 32768 + (wr * 128 + (qm * 4 + m) * 16 + fr) * 64;
            af[m * 2 + 0] = *(const bf16x8*)&smem[base + (fk ^ cswz)];
            af[m * 2 + 1] = *(const bf16x8*)&smem[base + ((32 + fk) ^ cswz)];
        }
    };
    auto ldB = [&](int b, int qn, bf16x8 (&bh)[4]) {
        #pragma unroll
        for (int n = 0; n < 2; ++n) {
            int base = b * 32768 + 16384 + (wc * 64 + qn * 32 + n * 16 + fr) * 64;
            bh[n * 2 + 0] = *(const bf16x8*)&smem[base + (fk ^ cswz)];
            bh[n * 2 + 1] = *(const bf16x8*)&smem[base + ((32 + fk) ^ cswz)];
        }
    };
    auto mma = [&](int qm, int qn, bf16x8 (&bh)[4]) {
        __builtin_amdgcn_s_setprio(1);
        #pragma unroll
        for (int m = 0; m < 4; ++m)
            #pragma unroll
            for (int n = 0; n < 2; ++n) {
                acc[qm*4+m][qn*2+n] = __builtin_amdgcn_mfma_f32_16x16x32_bf16(
                    af[m*2+0], bh[n*2+0], acc[qm*4+m][qn*2+n], 0, 0, 0);
                acc[qm*4+m][qn*2+n] = __builtin_amdgcn_mfma_f32_16x16x32_bf16(
                    af[m*2+1], bh[n*2+1], acc[qm*4+m][qn*2+n], 0, 0, 0);
            }
        __builtin_amdgcn_s_setprio(0);
    };
    #define BAR() __builtin_amdgcn_s_barrier()
    #define VM4() asm volatile("s_waitcnt vmcnt(4)" ::: "memory")

    stB(0, 0, 0); stB(0, 1, 0); stA(0, 0, 0); stA(0, 1, 0);
    stB(1, 0, 1); stB(1, 1, 1);
    VM4();
    BAR();

    for (int i = 0; i < 32; ++i) {
        const int t = 2 * i;
        const int kt2 = (t + 2 < 64) ? t + 2 : 63;
        const int kt3 = (t + 3 < 64) ? t + 3 : 63;
        ldA(0, 0); ldB(0, 0, bh0);
        stA(1, 0, t + 1);
        BAR(); mma(0, 0, bh0);
        ldB(0, 1, bh1);
        stA(1, 1, t + 1);
        BAR(); mma(0, 1, bh1);
        ldA(0, 1);
        BAR(); mma(1, 1, bh1);
        stB(0, 0, kt2); stB(0, 1, kt2);
        VM4();
        BAR(); mma(1, 0, bh0);
        ldA(1, 0); ldB(1, 0, bh0);
        stA(0, 0, kt2);
        BAR(); mma(0, 0, bh0);
        ldB(1, 1, bh1);
        stA(0, 1, kt2);
        BAR(); mma(0, 1, bh1);
        ldA(1, 1);
        BAR(); mma(1, 1, bh1);
        stB(1, 0, kt3); stB(1, 1, kt3);
        VM4();
        BAR(); mma(1, 0, bh0);
    }
    #undef BAR
    #undef VM4

    const int cc = lane & 15;
    const int cr = (lane >> 4) * 4;
    #pragma unroll
    for (int m = 0; m < 8; ++m) {
        #pragma unroll
        for (int n = 0; n < 4; ++n) {
            size_t row = rowA0 + wr * 128 + m * 16 + cr;
            size_t col = rowB0 + wc * 64 + n * 16 + cc;
            float bv = bias[col];
            #pragma unroll
            for (int q = 0; q < 4; ++q) {
                size_t idx = (row + q) * (size_t)N + col;
                float v = acc[m][n][q] + bv;
                if (MODE == 1) v = res[idx] + fmaxf(v, 0.0f);
                out[idx] = v;
            }
        }
    }
}

// ---------- LayerNorm + wgen + softmax (8 rows per block, eb-outer wgen) ----------
__global__ __launch_bounds__(256)
void ln_wgen(const float* __restrict__ h, const float* __restrict__ g,
             const float* __restrict__ beta, const float* __restrict__ WgT,
             const float* __restrict__ bg, u16* __restrict__ y,
             float* __restrict__ w) {
    __shared__ u32 ylp[8][2048];   // 8 rows of bf16 pairs, 64 KB
    __shared__ float red[8];
    __shared__ float wraw[8][40];

    int tid = threadIdx.x, lane = tid & 63, wv = tid >> 6;
    size_t row0 = (size_t)blockIdx.x * 8;

    for (int r = 0; r < 8; ++r) {
        const float4* hr = (const float4*)(h + (row0 + r) * 4096);
        float4 v[4];
        float s = 0.f, ss = 0.f;
        #pragma unroll
        for (int i = 0; i < 4; ++i) {
            v[i] = hr[tid + i * 256];
            s  += v[i].x + v[i].y + v[i].z + v[i].w;
            ss += v[i].x * v[i].x + v[i].y * v[i].y + v[i].z * v[i].z + v[i].w * v[i].w;
        }
        s = wred(s); ss = wred(ss);
        if (lane == 0) { red[wv] = s; red[4 + wv] = ss; }
        __syncthreads();
        float S = red[0] + red[1] + red[2] + red[3];
        float SS = red[4] + red[5] + red[6] + red[7];
        float mu = S * (1.0f / 4096.0f);
        float var = SS * (1.0f / 4096.0f) - mu * mu;
        float inv = rsqrtf(var + 1e-5f);
        u16* yr = y + (row0 + r) * 4096;
        #pragma unroll
        for (int i = 0; i < 4; ++i) {
            int base = tid + i * 256;           // float4 index
            float4 gv = ((const float4*)g)[base];
            float4 bv = ((const float4*)beta)[base];
            float o0 = (v[i].x - mu) * inv * gv.x + bv.x;
            float o1 = (v[i].y - mu) * inv * gv.y + bv.y;
            float o2 = (v[i].z - mu) * inv * gv.z + bv.z;
            float o3 = (v[i].w - mu) * inv * gv.w + bv.w;
            u32 p01 = (u32)f2bf(o0) | ((u32)f2bf(o1) << 16);
            u32 p23 = (u32)f2bf(o2) | ((u32)f2bf(o3) << 16);
            ylp[r][base * 2]     = p01;
            ylp[r][base * 2 + 1] = p23;
            uint2 pk; pk.x = p01; pk.y = p23;
            *(uint2*)(yr + base * 4) = pk;
        }
        __syncthreads();   // protects red for next row, ylp before wgen
    }

    // wgen: wave wv owns cols wv*10..wv*10+9; eb-outer so ylp is read once per eb
    float acc[8][10];
    #pragma unroll
    for (int r = 0; r < 8; ++r)
        #pragma unroll
        for (int c = 0; c < 10; ++c) acc[r][c] = 0.f;

    for (int eb = lane; eb < 2048; eb += 64) {
        float alo[8], ahi[8];
        #pragma unroll
        for (int r = 0; r < 8; ++r) {
            u32 a = ylp[r][eb];
            alo[r] = bf2f((u16)a);
            ahi[r] = bf2f((u16)(a >> 16));
        }
        #pragma unroll
        for (int c0 = 0; c0 < 10; ++c0) {
            int c = wv * 10 + c0;
            float2 wg = ((const float2*)(WgT + (size_t)c * 4096))[eb];
            #pragma unroll
            for (int r = 0; r < 8; ++r)
                acc[r][c0] += alo[r] * wg.x + ahi[r] * wg.y;
        }
    }
    #pragma unroll
    for (int r = 0; r < 8; ++r) {
        #pragma unroll
        for (int c0 = 0; c0 < 10; ++c0) {
            float p = wred(acc[r][c0]);
            if (lane == 0) wraw[r][wv * 10 + c0] = p + bg[wv * 10 + c0];
        }
    }
    __syncthreads();

    if (tid < 64) {
        int r = tid >> 3, hh = tid & 7;
        float e5[5];
        float mx = -1e30f;
        #pragma unroll
        for (int k = 0; k < 5; ++k) mx = fmaxf(mx, wraw[r][hh * 5 + k]);
        float sum = 0.f;
        #pragma unroll
        for (int k = 0; k < 5; ++k) { e5[k] = expf(wraw[r][hh * 5 + k] - mx); sum += e5[k]; }
        float isum = 1.0f / sum;
        float* wp = w + (row0 + r) * 40 + hh * 5;
        #pragma unroll
        for (int k = 0; k < 5; ++k) wp[k] = e5[k] * isum;
    }
}

// ---------- dynamic causal depthwise conv, register-ring version ----------
// Block: 30 consecutive t of one batch x 2048 channels. Thread: 8 channels,
// 5-tap f32 ring in registers, 5-unrolled so ring indices are compile-time.
__global__ __launch_bounds__(256)
void dconv2(const u16* __restrict__ y, const float* __restrict__ w,
            u16* __restrict__ conv) {
    int bid = blockIdx.x;             // 8 b * 18 tc * 2 half = 288
    int half = bid & 1;
    int rem = bid >> 1;
    int tc = rem % 18, b = rem / 18;
    int t0 = tc * 30;
    int d0 = half * 2048 + threadIdx.x * 8;
    int head = d0 >> 9;
    const u16* yb = y + (size_t)b * 512 * 4096 + d0;
    u16* cb = conv + (size_t)b * 512 * 4096 + d0;
    const float* wb = w + ((size_t)b * 512) * 40 + head * 5;

    float ring[5][8];
    #pragma unroll
    for (int j = 0; j < 4; ++j) {      // taps t0-4..t0-1 -> slots 1..4
        int tt = t0 - 4 + j;
        if (tt >= 0) {
            uint4 v = *(const uint4*)(yb + (size_t)tt * 4096);
            const u16* us = (const u16*)&v;
            #pragma unroll
            for (int e = 0; e < 8; ++e) ring[j + 1][e] = bf2f(us[e]);
        } else {
            #pragma unroll
            for (int e = 0; e < 8; ++e) ring[j + 1][e] = 0.f;
        }
    }

    for (int tt = 0; tt < 30; tt += 5) {
        #pragma unroll
        for (int j = 0; j < 5; ++j) {      // t = t0+tt+j, t % 5 == j
            int t = t0 + tt + j;
            if (t < 512) {
                uint4 v = *(const uint4*)(yb + (size_t)t * 4096);
                const u16* us = (const u16*)&v;
                #pragma unroll
                for (int e = 0; e < 8; ++e) ring[j][e] = bf2f(us[e]);
                const float* wt = wb + (size_t)t * 40;
                float w0 = wt[0], w1 = wt[1], w2 = wt[2], w3 = wt[3], w4 = wt[4];
                u16 o[8];
                #pragma unroll
                for (int e = 0; e < 8; ++e) {
                    // tap k uses slot (j+1+k)%5
                    float a = w0 * ring[(j + 1) % 5][e]
                            + w1 * ring[(j + 2) % 5][e]
                            + w2 * ring[(j + 3) % 5][e]
                            + w3 * ring[(j + 4) % 5][e]
                            + w4 * ring[j][e];
                    o[e] = f2bf(a);
                }
                *(uint4*)(cb + (size_t)t * 4096) = *(uint4*)o;
            }
        }
    }
}

// ---------- launcher ----------
extern "C" void kernel_launch(void* const* d_in, const int* in_sizes, int n_in,
                              void* d_out, int out_size, void* d_ws, size_t ws_size,
                              hipStream_t stream) {
    const float* x      = (const float*)d_in[0];
    const float* W_proj = (const float*)d_in[1];
    const float* b_proj = (const float*)d_in[2];
    const float* ln_g   = (const float*)d_in[3];
    const float* ln_b   = (const float*)d_in[4];
    const float* W_wgen = (const float*)d_in[5];
    const float* b_wgen = (const float*)d_in[6];
    const float* W_ff   = (const float*)d_in[7];
    const float* b_ff   = (const float*)d_in[8];
    float* out = (float*)d_out;

    char* ws = (char*)d_ws;
    u16* xb   = (u16*)(ws);                          // 32 MB, later reused as conv
    u16* WpT  = (u16*)(ws + ((size_t)32 << 20));     // 32 MB, later reused as y
    u16* WfT  = (u16*)(ws + ((size_t)64 << 20));     // 32 MB
    float* wbuf = (float*)(ws + ((size_t)96 << 20)); // 640 KB
    float* WgT  = (float*)(ws + ((size_t)97 << 20)); // 640 KB
    u16* conv = xb;
    u16* ybuf = WpT;

    cvt_f32_bf16<<<16384, 256, 0, stream>>>(x, xb);
    dim3 tb(32, 8);
    transpose_cvt<<<dim3(64, 64), tb, 0, stream>>>(W_proj, WpT);
    transpose_cvt<<<dim3(64, 64), tb, 0, stream>>>(W_ff, WfT);
    transpose_wgen<<<640, 256, 0, stream>>>(W_wgen, WgT);

    gemm256<0><<<256, 512, 0, stream>>>(xb, WpT, b_proj, nullptr, out);
    ln_wgen<<<512, 256, 0, stream>>>(out, ln_g, ln_b, WgT, b_wgen, ybuf, wbuf);
    dconv2<<<288, 256, 0, stream>>>(ybuf, wbuf, conv);
    gemm256<1><<<256, 512, 0, stream>>>(conv, WfT, b_ff, out, out);
}